// Round 22
// baseline (51.012 us; speedup 1.0000x reference)
//
#include <hip/hip_runtime.h>

#define BB 8
#define CC 128
#define HH 64
#define WW 64
#define K2 9
#define NOFF 18
#define HW 4096          // HH*WW
#define NPIX 32768       // BB*HW
#define OPAD 32          // o padded to 32 (2 N-tiles)
#define HP 66            // padded spatial dim
#define PSTRIDE (HP*HP*CC)   // elems per batch (padded)

#define TR_BLOCKS     4096  // 128 p-tiles x 4 c-tiles x 8 b
#define WF_BLOCKS     288   // 144 frags x 512 elems / 256
#define BORDER_BLOCKS 260   // 2 bufs x 2080 cells x 16 uint4 / 256

#define GR_ROW 1056         // granules (16B) per row per buf: 66 px x 16
#define ROWSET_BYTES 33792  // 2 bufs x 1056 x 16

typedef __attribute__((ext_vector_type(8))) short bf16x8;
typedef __attribute__((ext_vector_type(4))) float f32x4;

__device__ __forceinline__ unsigned short f2bf(float f) {
    unsigned u = __float_as_uint(f);
    unsigned r = u + 0x7FFFu + ((u >> 16) & 1u);   // RNE
    return (unsigned short)(r >> 16);
}
__device__ __forceinline__ float bf2f(unsigned short h) {
    return __uint_as_float((unsigned)h << 16);
}

// ---------------------------------------------------------------------------
// K0: fused prep (R19-verified).
//  [0,TR)        : transpose x -> xPh/xPl (hi/lo, zero-padded [b][66][66][128])
//  [TR,+WF)      : weights -> wF fragment-major (contiguous 16B/lane reads)
//  [.., +BORDER) : zero the 1-px border of xPh/xPl
// ---------------------------------------------------------------------------
__global__ __launch_bounds__(256) void prep_transpose_kernel(
    const float* __restrict__ x, const float* __restrict__ offw,
    unsigned short* __restrict__ xPh, unsigned short* __restrict__ xPl,
    unsigned short* __restrict__ wF)
{
    __shared__ float tile[32][33];
    int bi = blockIdx.x;
    int tid = threadIdx.x;
    if (bi < TR_BLOCKS) {
        int p0 = (bi & 127) * 32;
        int c0 = ((bi >> 7) & 3) * 32;
        int b  = bi >> 9;
        int tx = tid & 31;
        int ty = tid >> 5;                 // 0..7
#pragma unroll
        for (int i = 0; i < 4; ++i)
            tile[ty + i * 8][tx] =
                x[((size_t)(b * CC + c0 + ty + i * 8)) * HW + p0 + tx];
        __syncthreads();
#pragma unroll
        for (int i = 0; i < 4; ++i) {
            int p = p0 + ty + i * 8;
            int h = p >> 6, w = p & 63;
            float v = tile[tx][ty + i * 8];
            unsigned short hi = f2bf(v);
            unsigned short lo = f2bf(v - bf2f(hi));
            size_t pidx = ((size_t)b * HP * HP + (size_t)(h + 1) * HP + (w + 1)) * CC + c0 + tx;
            xPh[pidx] = hi;
            xPl[pidx] = lo;
        }
    } else if (bi < TR_BLOCKS + WF_BLOCKS) {
        int e = (bi - TR_BLOCKS) * 256 + tid;   // 0..73727
        int fid = e >> 9;
        int r = e & 511;
        int lane = r >> 3;
        int elem = r & 7;
        int bufsel = fid & 1;
        int n   = (fid >> 1) & 1;
        int cwv = (fid >> 2) & 3;
        int j   = fid >> 4;
        int o = n * 16 + (lane & 15);
        int c = cwv * 32 + ((lane >> 4) << 3) + elem;
        float v = (o < NOFF) ? offw[((size_t)o * CC + c) * K2 + j] : 0.f;
        unsigned short hi = f2bf(v);
        wF[e] = bufsel ? f2bf(v - bf2f(hi)) : hi;
    } else {
        int i = (bi - TR_BLOCKS - WF_BLOCKS) * 256 + tid;   // 0..66559
        int bufsel = i >= 33280;
        int jj = i - bufsel * 33280;
        int cell = jj >> 4, q = jj & 15;
        int b = cell / 260, r = cell - b * 260;
        int hp, wp;
        if (r < 132) { hp = (r >= 66) ? (HP - 1) : 0; wp = (r >= 66) ? r - 66 : r; }
        else { int r2 = r - 132; wp = (r2 & 1) ? (HP - 1) : 0; hp = 1 + (r2 >> 1); }
        unsigned short* dst = bufsel ? xPl : xPh;
        uint4 z = {0u, 0u, 0u, 0u};
        *(uint4*)(dst + (((size_t)b * HP + hp) * HP + wp) * CC + q * 8) = z;
    }
}

// ---------------------------------------------------------------------------
// K1: FUSED offset-conv (MFMA, LDS-staged A) + bilinear sample — R20-verified
// structure, now __launch_bounds__(256,3): LDS 52.2 KB x 3 = 156.7 KB fits
// 160 KB/CU, VGPR cap 170 >> measured 100 -> 3 blocks/CU (12 waves), 1.5x
// the TLP so gather loads of one block hide under another's MFMAs.
// ---------------------------------------------------------------------------
__global__ __launch_bounds__(256, 3) void fused_conv_sample_kernel(
    const unsigned short* __restrict__ xPh, const unsigned short* __restrict__ xPl,
    const unsigned short* __restrict__ wF, const float* __restrict__ offb,
    const float* __restrict__ wk, float* __restrict__ out)
{
    __shared__ __align__(16) unsigned char LDSB[ROWSET_BYTES];   // 33 KB (staging/red/acc_s)
    __shared__ float4 recW[576];   // 9.2 KB
    __shared__ int2   recI[576];   // 4.6 KB
    __shared__ float  swkT[K2 * CC];  // 4.6 KB
    int jx = blockIdx.x;        // 0..511
    int b = jx & 7;             // XCD-local batch
    int h = jx >> 3;            // 0..63
    int tid = threadIdx.x;
    int l = tid & 63;
    int cw = __builtin_amdgcn_readfirstlane(tid >> 6);   // 0..3 c-chunk
    int row  = l & 15;          // A: M-row ; B: o-col
    int kseg = l >> 4;          // 0..3
    int cslot = cw * 4 + kseg;  // 16B channel-slot

    // tap weights (transposed) — once per block
    for (int i = tid; i < K2 * CC; i += 256) {
        int c = i / 9, t = i - c * 9;
        swkT[t * CC + c] = wk[i];
    }

    f32x4 acc[4][2];
#pragma unroll
    for (int m = 0; m < 4; ++m)
#pragma unroll
        for (int n = 0; n < 2; ++n)
            acc[m][n] = (f32x4){0.f, 0.f, 0.f, 0.f};

    const unsigned short* xh = xPh + (size_t)b * PSTRIDE;
    const unsigned short* xl = xPl + (size_t)b * PSTRIDE;

    // ---------------- Phase 1: conv (R19 structure) ----------------
#pragma unroll 1
    for (int dh = 0; dh < 3; ++dh) {
        if (dh) __syncthreads();
        const unsigned short* rowh = xh + ((size_t)(h + dh) * HP) * CC;
        const unsigned short* rowl = xl + ((size_t)(h + dh) * HP) * CC;
#pragma unroll
        for (int it = 0; it < 9; ++it) {
            int G = it * 256 + tid;
            if (G < 2112) {
                int buf = G >= GR_ROW;
                int g = G - (buf ? GR_ROW : 0);
                int px = g >> 4, cg = g & 15;
                const unsigned short* src =
                    (buf ? rowl : rowh) + (size_t)px * CC + ((cg ^ (px & 7)) << 3);
                uint4 v = *(const uint4*)src;
                *(uint4*)(LDSB + (size_t)G * 16) = v;
            }
        }
        __syncthreads();
#pragma unroll
        for (int dw = 0; dw < 3; ++dw) {
            int j = dh * 3 + dw;
            int fbase = (j * 4 + cw) * 4;
            bf16x8 Bh0 = *(const bf16x8*)(wF + (size_t)(fbase + 0) * 512 + l * 8);
            bf16x8 Bl0 = *(const bf16x8*)(wF + (size_t)(fbase + 1) * 512 + l * 8);
            bf16x8 Bh1 = *(const bf16x8*)(wF + (size_t)(fbase + 2) * 512 + l * 8);
            bf16x8 Bl1 = *(const bf16x8*)(wF + (size_t)(fbase + 3) * 512 + l * 8);
#pragma unroll
            for (int m = 0; m < 4; ++m) {
                int px = m * 16 + row + dw;
                int gA = px * 16 + (cslot ^ (px & 7));
                bf16x8 Ah = *(const bf16x8*)(LDSB + (size_t)gA * 16);
                bf16x8 Al = *(const bf16x8*)(LDSB + (size_t)(GR_ROW + gA) * 16);
                acc[m][0] = __builtin_amdgcn_mfma_f32_16x16x32_bf16(Ah, Bh0, acc[m][0], 0, 0, 0);
                acc[m][0] = __builtin_amdgcn_mfma_f32_16x16x32_bf16(Al, Bh0, acc[m][0], 0, 0, 0);
                acc[m][0] = __builtin_amdgcn_mfma_f32_16x16x32_bf16(Ah, Bl0, acc[m][0], 0, 0, 0);
                acc[m][1] = __builtin_amdgcn_mfma_f32_16x16x32_bf16(Ah, Bh1, acc[m][1], 0, 0, 0);
                acc[m][1] = __builtin_amdgcn_mfma_f32_16x16x32_bf16(Al, Bh1, acc[m][1], 0, 0, 0);
                acc[m][1] = __builtin_amdgcn_mfma_f32_16x16x32_bf16(Ah, Bl1, acc[m][1], 0, 0, 0);
            }
        }
    }

    // ---------------- Phase 2: reduce + records (once per row) ----------------
    __syncthreads();
    float (*red)[OPAD][65] = (float (*)[OPAD][65])LDSB;   // aliases staging
#pragma unroll
    for (int m = 0; m < 4; ++m)
#pragma unroll
        for (int n = 0; n < 2; ++n)
#pragma unroll
            for (int r = 0; r < 4; ++r)
                red[cw][n * 16 + row][m * 16 + kseg * 4 + r] = acc[m][n][r];
    __syncthreads();

    float base_y = -1.f + (2.f / (HH - 1)) * (float)h;
    for (int item = tid; item < 576; item += 256) {
        int p = item & 63;
        int t = item >> 6;       // 0..8
        float sx = offb[t]
                 + red[0][t][p] + red[1][t][p] + red[2][t][p] + red[3][t][p];
        float sy = offb[t + K2]
                 + red[0][t + K2][p] + red[1][t + K2][p]
                 + red[2][t + K2][p] + red[3][t + K2][p];
        float base_x = -1.f + (2.f / (WW - 1)) * (float)p;
        float gx = ((sx + base_x + 1.f) * (float)WW - 1.f) * 0.5f;
        float gy = ((sy + base_y + 1.f) * (float)HH - 1.f) * 0.5f;

        float x0f = floorf(gx), y0f = floorf(gy);
        float wx1 = gx - x0f, wx0 = 1.f - wx1;
        float wy1 = gy - y0f, wy0 = 1.f - wy1;
        int ix0 = (int)x0f, iy0 = (int)y0f;
        int ix1 = ix0 + 1,  iy1 = iy0 + 1;
        float ax0 = ((unsigned)ix0 < WW) ? wx0 : 0.f;
        float ax1 = ((unsigned)ix1 < WW) ? wx1 : 0.f;
        float ay0 = ((unsigned)iy0 < HH) ? wy0 : 0.f;
        float ay1 = ((unsigned)iy1 < HH) ? wy1 : 0.f;
        int cx0 = min(max(ix0, 0), WW - 1) + 1, cx1 = min(max(ix1, 0), WW - 1) + 1;
        int cy0 = min(max(iy0, 0), HH - 1) + 1, cy1 = min(max(iy1, 0), HH - 1) + 1;
        int o00 = cy0 * HP + cx0, o10 = cy0 * HP + cx1;
        int o01 = cy1 * HP + cx0, o11 = cy1 * HP + cx1;
        recW[t * 64 + p] = make_float4(ax0 * ay0, ax1 * ay0, ax0 * ay1, ax1 * ay1);
        recI[t * 64 + p] = make_int2(o00 | (o10 << 16), o01 | (o11 << 16));
    }
    __syncthreads();

    // ---------------- Phase 3: gather + tap-weighted sum ----------------
    int c8     = (tid & 15) * 8;
    int slot16 = tid >> 4;           // 0..15
    const unsigned short* xb = xh;   // padded hi buffer
    float* acc_s = (float*)LDSB;     // 16*132 floats, aliases dead staging

    float4 wkA[K2], wkB[K2];
#pragma unroll
    for (int t = 0; t < K2; ++t) {
        wkA[t] = *(const float4*)&swkT[t * CC + c8];
        wkB[t] = *(const float4*)&swkT[t * CC + c8 + 4];
    }

#pragma unroll 1
    for (int pp = 0; pp < 4; ++pp) {
        int slot = pp * 16 + slot16;
        float acc8[8];
#pragma unroll
        for (int i = 0; i < 8; ++i) acc8[i] = 0.f;
#pragma unroll
        for (int t = 0; t < K2; ++t) {
            int r = t * 64 + slot;
            float4 wv = recW[r];
            int2   iv = recI[r];
            uint4 u00 = *(const uint4*)(xb + (((iv.x & 0xFFFF) << 7) + c8));
            uint4 u10 = *(const uint4*)(xb + (((iv.x >> 16)     << 7) + c8));
            uint4 u01 = *(const uint4*)(xb + (((iv.y & 0xFFFF) << 7) + c8));
            uint4 u11 = *(const uint4*)(xb + (((iv.y >> 16)     << 7) + c8));
            const unsigned* p00 = (const unsigned*)&u00;
            const unsigned* p10 = (const unsigned*)&u10;
            const unsigned* p01 = (const unsigned*)&u01;
            const unsigned* p11 = (const unsigned*)&u11;
#pragma unroll
            for (int g = 0; g < 4; ++g) {
                float v00a = __uint_as_float(p00[g] << 16);
                float v00b = __uint_as_float(p00[g] & 0xFFFF0000u);
                float v10a = __uint_as_float(p10[g] << 16);
                float v10b = __uint_as_float(p10[g] & 0xFFFF0000u);
                float v01a = __uint_as_float(p01[g] << 16);
                float v01b = __uint_as_float(p01[g] & 0xFFFF0000u);
                float v11a = __uint_as_float(p11[g] << 16);
                float v11b = __uint_as_float(p11[g] & 0xFFFF0000u);
                float bila = fmaf(v00a, wv.x, fmaf(v10a, wv.y, fmaf(v01a, wv.z, v11a * wv.w)));
                float bilb = fmaf(v00b, wv.x, fmaf(v10b, wv.y, fmaf(v01b, wv.z, v11b * wv.w)));
                float wka = (g < 2) ? ((g == 0) ? wkA[t].x : wkA[t].z)
                                    : ((g == 2) ? wkB[t].x : wkB[t].z);
                float wkb = (g < 2) ? ((g == 0) ? wkA[t].y : wkA[t].w)
                                    : ((g == 2) ? wkB[t].y : wkB[t].w);
                acc8[g * 2]     = fmaf(bila, wka, acc8[g * 2]);
                acc8[g * 2 + 1] = fmaf(bilb, wkb, acc8[g * 2 + 1]);
            }
        }
        __syncthreads();   // acc_s free (prev pp reads done / staging dead)
        *(float4*)&acc_s[slot16 * 132 + c8]     = make_float4(acc8[0], acc8[1], acc8[2], acc8[3]);
        *(float4*)&acc_s[slot16 * 132 + c8 + 4] = make_float4(acc8[4], acc8[5], acc8[6], acc8[7]);
        __syncthreads();
#pragma unroll
        for (int r = 0; r < 8; ++r) {
            int cs   = r * 16 + (tid >> 4);
            int wloc = tid & 15;
            out[((size_t)(b * CC + cs)) * HW + h * WW + pp * 16 + wloc] =
                acc_s[wloc * 132 + cs];
        }
    }
}

// ---------------------------------------------------------------------------
// Fallback (round-1 pipeline, needs only 2.36 MB ws) — defensive only.
// ---------------------------------------------------------------------------
__global__ __launch_bounds__(256) void offset_grid_kernel_fb(
    const float* __restrict__ x, const float* __restrict__ offw,
    const float* __restrict__ offb, float* __restrict__ grid)
{
    int idx = blockIdx.x * blockDim.x + threadIdx.x;
    if (idx >= NPIX) return;
    int w = idx & 63, h = (idx >> 6) & 63, b = idx >> 12;
    float acc[NOFF];
#pragma unroll
    for (int o = 0; o < NOFF; ++o) acc[o] = offb[o];
    for (int c = 0; c < CC; ++c) {
        const float* xp = x + ((size_t)(b * CC + c)) * HW;
        float xv[9];
#pragma unroll
        for (int dh = -1; dh <= 1; ++dh)
#pragma unroll
            for (int dw = -1; dw <= 1; ++dw) {
                int hh = h + dh, ww2 = w + dw;
                float v = 0.f;
                if (hh >= 0 && hh < HH && ww2 >= 0 && ww2 < WW) v = xp[hh * WW + ww2];
                xv[(dh + 1) * 3 + (dw + 1)] = v;
            }
#pragma unroll
        for (int o = 0; o < NOFF; ++o) {
            const float* wp = offw + (size_t)(o * CC + c) * 9;
#pragma unroll
            for (int jj = 0; jj < 9; ++jj) acc[o] = fmaf(xv[jj], wp[jj], acc[o]);
        }
    }
    float base_x = -1.f + (2.f / (WW - 1)) * (float)w;
    float base_y = -1.f + (2.f / (HH - 1)) * (float)h;
#pragma unroll
    for (int t = 0; t < K2; ++t) {
        float gx = ((acc[t]      + base_x + 1.f) * (float)WW - 1.f) * 0.5f;
        float gy = ((acc[K2 + t] + base_y + 1.f) * (float)HH - 1.f) * 0.5f;
        size_t gi = ((((size_t)b * K2 + t) * HH + h) * WW + w) * 2;
        grid[gi] = gx; grid[gi + 1] = gy;
    }
}

__global__ __launch_bounds__(256) void sample_kernel_fb(
    const float* __restrict__ x, const float* __restrict__ grid,
    const float* __restrict__ wk, float* __restrict__ out)
{
    int idx = blockIdx.x * blockDim.x + threadIdx.x;
    if (idx >= BB * CC * HW) return;
    int w = idx & 63, h = (idx >> 6) & 63;
    int c = (idx / HW) & 127, b = idx / (CC * HW);
    const float* xp = x + ((size_t)(b * CC + c)) * HW;
    const float2* gp = (const float2*)grid;
    float acc = 0.f;
#pragma unroll
    for (int t = 0; t < K2; ++t) {
        float2 g = gp[(((size_t)b * K2 + t)) * HW + h * WW + w];
        float gx = g.x, gy = g.y;
        float x0f = floorf(gx), y0f = floorf(gy);
        float wx1 = gx - x0f, wx0 = 1.f - wx1;
        float wy1 = gy - y0f, wy0 = 1.f - wy1;
        int ix0 = (int)x0f, iy0 = (int)y0f;
        int ix1 = ix0 + 1,  iy1 = iy0 + 1;
        float v00 = 0.f, v10 = 0.f, v01 = 0.f, v11 = 0.f;
        if ((unsigned)iy0 < HH) {
            const float* row = xp + (size_t)iy0 * WW;
            if ((unsigned)ix0 < WW) v00 = row[ix0];
            if ((unsigned)ix1 < WW) v10 = row[ix1];
        }
        if ((unsigned)iy1 < HH) {
            const float* row = xp + (size_t)iy1 * WW;
            if ((unsigned)ix0 < WW) v01 = row[ix0];
            if ((unsigned)ix1 < WW) v11 = row[ix1];
        }
        float bil = v00 * (wx0 * wy0) + v10 * (wx1 * wy0)
                  + v01 * (wx0 * wy1) + v11 * (wx1 * wy1);
        acc = fmaf(bil, wk[c * K2 + t], acc);
    }
    out[idx] = acc;
}

extern "C" void kernel_launch(void* const* d_in, const int* in_sizes, int n_in,
                              void* d_out, int out_size, void* d_ws, size_t ws_size,
                              hipStream_t stream) {
    const float* x    = (const float*)d_in[0];
    const float* offw = (const float*)d_in[1];
    const float* offb = (const float*)d_in[2];
    const float* wwk  = (const float*)d_in[3];
    float* out = (float*)d_out;

    const size_t XP_BYTES = (size_t)BB * PSTRIDE * sizeof(unsigned short); // 8.92 MB
    const size_t WF_BYTES = (size_t)144 * 512 * sizeof(unsigned short);    // 147 KB
    const size_t NEED = 2 * XP_BYTES + WF_BYTES;                           // 18.0 MB

    if (ws_size < NEED) {
        float* grid = (float*)d_ws;
        hipLaunchKernelGGL(offset_grid_kernel_fb, dim3(NPIX / 256), dim3(256),
                           0, stream, x, offw, offb, grid);
        hipLaunchKernelGGL(sample_kernel_fb, dim3((BB * CC * HW) / 256), dim3(256),
                           0, stream, x, grid, wwk, out);
        return;
    }

    // ws: [xPh][xPl][wF]
    char* p = (char*)d_ws;
    unsigned short* xPh = (unsigned short*)p;           p += XP_BYTES;
    unsigned short* xPl = (unsigned short*)p;           p += XP_BYTES;
    unsigned short* wF  = (unsigned short*)p;

    hipLaunchKernelGGL(prep_transpose_kernel,
                       dim3(TR_BLOCKS + WF_BLOCKS + BORDER_BLOCKS), dim3(256),
                       0, stream, x, offw, xPh, xPl, wF);
    hipLaunchKernelGGL(fused_conv_sample_kernel, dim3(512), dim3(256),
                       0, stream, xPh, xPl, wF, offb, wwk, out);
}

// Round 23
// 44.937 us; speedup vs baseline: 1.1352x; 1.1352x over previous
//
#include <hip/hip_runtime.h>

#define BB 8
#define CC 128
#define HH 64
#define WW 64
#define K2 9
#define NOFF 18
#define HW 4096          // HH*WW
#define NPIX 32768       // BB*HW
#define OPAD 32          // o padded to 32 (2 N-tiles)
#define HP 66            // padded spatial dim
#define PSTRIDE (HP*HP*CC)   // elems per batch (padded)

#define TR_BLOCKS     4096  // 128 p-tiles x 4 c-tiles x 8 b
#define WF_BLOCKS     288   // 144 frags x 512 elems / 256
#define BORDER_BLOCKS 260   // 2 bufs x 2080 cells x 16 uint4 / 256

#define GR_ROW 1056         // granules (16B) per row per buf: 66 px x 16
#define ROWSET_BYTES 33792  // 2 bufs x 1056 x 16

typedef __attribute__((ext_vector_type(8))) short bf16x8;
typedef __attribute__((ext_vector_type(4))) float f32x4;

__device__ __forceinline__ unsigned short f2bf(float f) {
    unsigned u = __float_as_uint(f);
    unsigned r = u + 0x7FFFu + ((u >> 16) & 1u);   // RNE
    return (unsigned short)(r >> 16);
}
__device__ __forceinline__ float bf2f(unsigned short h) {
    return __uint_as_float((unsigned)h << 16);
}

// ---------------------------------------------------------------------------
// K0: fused prep (R19-verified).
//  [0,TR)        : transpose x -> xPh/xPl (hi/lo, zero-padded [b][66][66][128])
//  [TR,+WF)      : weights -> wF fragment-major (contiguous 16B/lane reads)
//  [.., +BORDER) : zero the 1-px border of xPh/xPl
// ---------------------------------------------------------------------------
__global__ __launch_bounds__(256) void prep_transpose_kernel(
    const float* __restrict__ x, const float* __restrict__ offw,
    unsigned short* __restrict__ xPh, unsigned short* __restrict__ xPl,
    unsigned short* __restrict__ wF)
{
    __shared__ float tile[32][33];
    int bi = blockIdx.x;
    int tid = threadIdx.x;
    if (bi < TR_BLOCKS) {
        int p0 = (bi & 127) * 32;
        int c0 = ((bi >> 7) & 3) * 32;
        int b  = bi >> 9;
        int tx = tid & 31;
        int ty = tid >> 5;                 // 0..7
#pragma unroll
        for (int i = 0; i < 4; ++i)
            tile[ty + i * 8][tx] =
                x[((size_t)(b * CC + c0 + ty + i * 8)) * HW + p0 + tx];
        __syncthreads();
#pragma unroll
        for (int i = 0; i < 4; ++i) {
            int p = p0 + ty + i * 8;
            int h = p >> 6, w = p & 63;
            float v = tile[tx][ty + i * 8];
            unsigned short hi = f2bf(v);
            unsigned short lo = f2bf(v - bf2f(hi));
            size_t pidx = ((size_t)b * HP * HP + (size_t)(h + 1) * HP + (w + 1)) * CC + c0 + tx;
            xPh[pidx] = hi;
            xPl[pidx] = lo;
        }
    } else if (bi < TR_BLOCKS + WF_BLOCKS) {
        int e = (bi - TR_BLOCKS) * 256 + tid;   // 0..73727
        int fid = e >> 9;
        int r = e & 511;
        int lane = r >> 3;
        int elem = r & 7;
        int bufsel = fid & 1;
        int n   = (fid >> 1) & 1;
        int cwv = (fid >> 2) & 3;
        int j   = fid >> 4;
        int o = n * 16 + (lane & 15);
        int c = cwv * 32 + ((lane >> 4) << 3) + elem;
        float v = (o < NOFF) ? offw[((size_t)o * CC + c) * K2 + j] : 0.f;
        unsigned short hi = f2bf(v);
        wF[e] = bufsel ? f2bf(v - bf2f(hi)) : hi;
    } else {
        int i = (bi - TR_BLOCKS - WF_BLOCKS) * 256 + tid;   // 0..66559
        int bufsel = i >= 33280;
        int jj = i - bufsel * 33280;
        int cell = jj >> 4, q = jj & 15;
        int b = cell / 260, r = cell - b * 260;
        int hp, wp;
        if (r < 132) { hp = (r >= 66) ? (HP - 1) : 0; wp = (r >= 66) ? r - 66 : r; }
        else { int r2 = r - 132; wp = (r2 & 1) ? (HP - 1) : 0; hp = 1 + (r2 >> 1); }
        unsigned short* dst = bufsel ? xPl : xPh;
        uint4 z = {0u, 0u, 0u, 0u};
        *(uint4*)(dst + (((size_t)b * HP + hp) * HP + wp) * CC + q * 8) = z;
    }
}

// ---------------------------------------------------------------------------
// K1: FUSED offset-conv (MFMA, LDS-staged A) + bilinear sample — R20-verified
// structure and bounds (256,2). HW already fits 3 blocks/CU at VGPR=100 /
// LDS=52.2 KB; declaring (256,3) only capped registers and caused spills
// (R22 lesson). Phase 1: conv via contiguous staged rows + ds_read_b128.
// Phase 2: reduce + 576 bilinear records once per row (LDS only).
// Phase 3: gather + tap-weighted sum, 4 passes of 16 px.
// ---------------------------------------------------------------------------
__global__ __launch_bounds__(256, 2) void fused_conv_sample_kernel(
    const unsigned short* __restrict__ xPh, const unsigned short* __restrict__ xPl,
    const unsigned short* __restrict__ wF, const float* __restrict__ offb,
    const float* __restrict__ wk, float* __restrict__ out)
{
    __shared__ __align__(16) unsigned char LDSB[ROWSET_BYTES];   // 33 KB (staging/red/acc_s)
    __shared__ float4 recW[576];   // 9.2 KB
    __shared__ int2   recI[576];   // 4.6 KB
    __shared__ float  swkT[K2 * CC];  // 4.6 KB
    int jx = blockIdx.x;        // 0..511
    int b = jx & 7;             // XCD-local batch
    int h = jx >> 3;            // 0..63
    int tid = threadIdx.x;
    int l = tid & 63;
    int cw = __builtin_amdgcn_readfirstlane(tid >> 6);   // 0..3 c-chunk
    int row  = l & 15;          // A: M-row ; B: o-col
    int kseg = l >> 4;          // 0..3
    int cslot = cw * 4 + kseg;  // 16B channel-slot

    // tap weights (transposed) — once per block
    for (int i = tid; i < K2 * CC; i += 256) {
        int c = i / 9, t = i - c * 9;
        swkT[t * CC + c] = wk[i];
    }

    f32x4 acc[4][2];
#pragma unroll
    for (int m = 0; m < 4; ++m)
#pragma unroll
        for (int n = 0; n < 2; ++n)
            acc[m][n] = (f32x4){0.f, 0.f, 0.f, 0.f};

    const unsigned short* xh = xPh + (size_t)b * PSTRIDE;
    const unsigned short* xl = xPl + (size_t)b * PSTRIDE;

    // ---------------- Phase 1: conv (R19 structure) ----------------
#pragma unroll 1
    for (int dh = 0; dh < 3; ++dh) {
        if (dh) __syncthreads();
        const unsigned short* rowh = xh + ((size_t)(h + dh) * HP) * CC;
        const unsigned short* rowl = xl + ((size_t)(h + dh) * HP) * CC;
#pragma unroll
        for (int it = 0; it < 9; ++it) {
            int G = it * 256 + tid;
            if (G < 2112) {
                int buf = G >= GR_ROW;
                int g = G - (buf ? GR_ROW : 0);
                int px = g >> 4, cg = g & 15;
                const unsigned short* src =
                    (buf ? rowl : rowh) + (size_t)px * CC + ((cg ^ (px & 7)) << 3);
                uint4 v = *(const uint4*)src;
                *(uint4*)(LDSB + (size_t)G * 16) = v;
            }
        }
        __syncthreads();
#pragma unroll
        for (int dw = 0; dw < 3; ++dw) {
            int j = dh * 3 + dw;
            int fbase = (j * 4 + cw) * 4;
            bf16x8 Bh0 = *(const bf16x8*)(wF + (size_t)(fbase + 0) * 512 + l * 8);
            bf16x8 Bl0 = *(const bf16x8*)(wF + (size_t)(fbase + 1) * 512 + l * 8);
            bf16x8 Bh1 = *(const bf16x8*)(wF + (size_t)(fbase + 2) * 512 + l * 8);
            bf16x8 Bl1 = *(const bf16x8*)(wF + (size_t)(fbase + 3) * 512 + l * 8);
#pragma unroll
            for (int m = 0; m < 4; ++m) {
                int px = m * 16 + row + dw;
                int gA = px * 16 + (cslot ^ (px & 7));
                bf16x8 Ah = *(const bf16x8*)(LDSB + (size_t)gA * 16);
                bf16x8 Al = *(const bf16x8*)(LDSB + (size_t)(GR_ROW + gA) * 16);
                acc[m][0] = __builtin_amdgcn_mfma_f32_16x16x32_bf16(Ah, Bh0, acc[m][0], 0, 0, 0);
                acc[m][0] = __builtin_amdgcn_mfma_f32_16x16x32_bf16(Al, Bh0, acc[m][0], 0, 0, 0);
                acc[m][0] = __builtin_amdgcn_mfma_f32_16x16x32_bf16(Ah, Bl0, acc[m][0], 0, 0, 0);
                acc[m][1] = __builtin_amdgcn_mfma_f32_16x16x32_bf16(Ah, Bh1, acc[m][1], 0, 0, 0);
                acc[m][1] = __builtin_amdgcn_mfma_f32_16x16x32_bf16(Al, Bh1, acc[m][1], 0, 0, 0);
                acc[m][1] = __builtin_amdgcn_mfma_f32_16x16x32_bf16(Ah, Bl1, acc[m][1], 0, 0, 0);
            }
        }
    }

    // ---------------- Phase 2: reduce + records (once per row) ----------------
    __syncthreads();
    float (*red)[OPAD][65] = (float (*)[OPAD][65])LDSB;   // aliases staging
#pragma unroll
    for (int m = 0; m < 4; ++m)
#pragma unroll
        for (int n = 0; n < 2; ++n)
#pragma unroll
            for (int r = 0; r < 4; ++r)
                red[cw][n * 16 + row][m * 16 + kseg * 4 + r] = acc[m][n][r];
    __syncthreads();

    float base_y = -1.f + (2.f / (HH - 1)) * (float)h;
    for (int item = tid; item < 576; item += 256) {
        int p = item & 63;
        int t = item >> 6;       // 0..8
        float sx = offb[t]
                 + red[0][t][p] + red[1][t][p] + red[2][t][p] + red[3][t][p];
        float sy = offb[t + K2]
                 + red[0][t + K2][p] + red[1][t + K2][p]
                 + red[2][t + K2][p] + red[3][t + K2][p];
        float base_x = -1.f + (2.f / (WW - 1)) * (float)p;
        float gx = ((sx + base_x + 1.f) * (float)WW - 1.f) * 0.5f;
        float gy = ((sy + base_y + 1.f) * (float)HH - 1.f) * 0.5f;

        float x0f = floorf(gx), y0f = floorf(gy);
        float wx1 = gx - x0f, wx0 = 1.f - wx1;
        float wy1 = gy - y0f, wy0 = 1.f - wy1;
        int ix0 = (int)x0f, iy0 = (int)y0f;
        int ix1 = ix0 + 1,  iy1 = iy0 + 1;
        float ax0 = ((unsigned)ix0 < WW) ? wx0 : 0.f;
        float ax1 = ((unsigned)ix1 < WW) ? wx1 : 0.f;
        float ay0 = ((unsigned)iy0 < HH) ? wy0 : 0.f;
        float ay1 = ((unsigned)iy1 < HH) ? wy1 : 0.f;
        int cx0 = min(max(ix0, 0), WW - 1) + 1, cx1 = min(max(ix1, 0), WW - 1) + 1;
        int cy0 = min(max(iy0, 0), HH - 1) + 1, cy1 = min(max(iy1, 0), HH - 1) + 1;
        int o00 = cy0 * HP + cx0, o10 = cy0 * HP + cx1;
        int o01 = cy1 * HP + cx0, o11 = cy1 * HP + cx1;
        recW[t * 64 + p] = make_float4(ax0 * ay0, ax1 * ay0, ax0 * ay1, ax1 * ay1);
        recI[t * 64 + p] = make_int2(o00 | (o10 << 16), o01 | (o11 << 16));
    }
    __syncthreads();

    // ---------------- Phase 3: gather + tap-weighted sum ----------------
    int c8     = (tid & 15) * 8;
    int slot16 = tid >> 4;           // 0..15
    const unsigned short* xb = xh;   // padded hi buffer
    float* acc_s = (float*)LDSB;     // 16*132 floats, aliases dead staging

    float4 wkA[K2], wkB[K2];
#pragma unroll
    for (int t = 0; t < K2; ++t) {
        wkA[t] = *(const float4*)&swkT[t * CC + c8];
        wkB[t] = *(const float4*)&swkT[t * CC + c8 + 4];
    }

#pragma unroll 1
    for (int pp = 0; pp < 4; ++pp) {
        int slot = pp * 16 + slot16;
        float acc8[8];
#pragma unroll
        for (int i = 0; i < 8; ++i) acc8[i] = 0.f;
#pragma unroll
        for (int t = 0; t < K2; ++t) {
            int r = t * 64 + slot;
            float4 wv = recW[r];
            int2   iv = recI[r];
            uint4 u00 = *(const uint4*)(xb + (((iv.x & 0xFFFF) << 7) + c8));
            uint4 u10 = *(const uint4*)(xb + (((iv.x >> 16)     << 7) + c8));
            uint4 u01 = *(const uint4*)(xb + (((iv.y & 0xFFFF) << 7) + c8));
            uint4 u11 = *(const uint4*)(xb + (((iv.y >> 16)     << 7) + c8));
            const unsigned* p00 = (const unsigned*)&u00;
            const unsigned* p10 = (const unsigned*)&u10;
            const unsigned* p01 = (const unsigned*)&u01;
            const unsigned* p11 = (const unsigned*)&u11;
#pragma unroll
            for (int g = 0; g < 4; ++g) {
                float v00a = __uint_as_float(p00[g] << 16);
                float v00b = __uint_as_float(p00[g] & 0xFFFF0000u);
                float v10a = __uint_as_float(p10[g] << 16);
                float v10b = __uint_as_float(p10[g] & 0xFFFF0000u);
                float v01a = __uint_as_float(p01[g] << 16);
                float v01b = __uint_as_float(p01[g] & 0xFFFF0000u);
                float v11a = __uint_as_float(p11[g] << 16);
                float v11b = __uint_as_float(p11[g] & 0xFFFF0000u);
                float bila = fmaf(v00a, wv.x, fmaf(v10a, wv.y, fmaf(v01a, wv.z, v11a * wv.w)));
                float bilb = fmaf(v00b, wv.x, fmaf(v10b, wv.y, fmaf(v01b, wv.z, v11b * wv.w)));
                float wka = (g < 2) ? ((g == 0) ? wkA[t].x : wkA[t].z)
                                    : ((g == 2) ? wkB[t].x : wkB[t].z);
                float wkb = (g < 2) ? ((g == 0) ? wkA[t].y : wkA[t].w)
                                    : ((g == 2) ? wkB[t].y : wkB[t].w);
                acc8[g * 2]     = fmaf(bila, wka, acc8[g * 2]);
                acc8[g * 2 + 1] = fmaf(bilb, wkb, acc8[g * 2 + 1]);
            }
        }
        __syncthreads();   // acc_s free (prev pp reads done / staging dead)
        *(float4*)&acc_s[slot16 * 132 + c8]     = make_float4(acc8[0], acc8[1], acc8[2], acc8[3]);
        *(float4*)&acc_s[slot16 * 132 + c8 + 4] = make_float4(acc8[4], acc8[5], acc8[6], acc8[7]);
        __syncthreads();
#pragma unroll
        for (int r = 0; r < 8; ++r) {
            int cs   = r * 16 + (tid >> 4);
            int wloc = tid & 15;
            out[((size_t)(b * CC + cs)) * HW + h * WW + pp * 16 + wloc] =
                acc_s[wloc * 132 + cs];
        }
    }
}

// ---------------------------------------------------------------------------
// Fallback (round-1 pipeline, needs only 2.36 MB ws) — defensive only.
// ---------------------------------------------------------------------------
__global__ __launch_bounds__(256) void offset_grid_kernel_fb(
    const float* __restrict__ x, const float* __restrict__ offw,
    const float* __restrict__ offb, float* __restrict__ grid)
{
    int idx = blockIdx.x * blockDim.x + threadIdx.x;
    if (idx >= NPIX) return;
    int w = idx & 63, h = (idx >> 6) & 63, b = idx >> 12;
    float acc[NOFF];
#pragma unroll
    for (int o = 0; o < NOFF; ++o) acc[o] = offb[o];
    for (int c = 0; c < CC; ++c) {
        const float* xp = x + ((size_t)(b * CC + c)) * HW;
        float xv[9];
#pragma unroll
        for (int dh = -1; dh <= 1; ++dh)
#pragma unroll
            for (int dw = -1; dw <= 1; ++dw) {
                int hh = h + dh, ww2 = w + dw;
                float v = 0.f;
                if (hh >= 0 && hh < HH && ww2 >= 0 && ww2 < WW) v = xp[hh * WW + ww2];
                xv[(dh + 1) * 3 + (dw + 1)] = v;
            }
#pragma unroll
        for (int o = 0; o < NOFF; ++o) {
            const float* wp = offw + (size_t)(o * CC + c) * 9;
#pragma unroll
            for (int jj = 0; jj < 9; ++jj) acc[o] = fmaf(xv[jj], wp[jj], acc[o]);
        }
    }
    float base_x = -1.f + (2.f / (WW - 1)) * (float)w;
    float base_y = -1.f + (2.f / (HH - 1)) * (float)h;
#pragma unroll
    for (int t = 0; t < K2; ++t) {
        float gx = ((acc[t]      + base_x + 1.f) * (float)WW - 1.f) * 0.5f;
        float gy = ((acc[K2 + t] + base_y + 1.f) * (float)HH - 1.f) * 0.5f;
        size_t gi = ((((size_t)b * K2 + t) * HH + h) * WW + w) * 2;
        grid[gi] = gx; grid[gi + 1] = gy;
    }
}

__global__ __launch_bounds__(256) void sample_kernel_fb(
    const float* __restrict__ x, const float* __restrict__ grid,
    const float* __restrict__ wk, float* __restrict__ out)
{
    int idx = blockIdx.x * blockDim.x + threadIdx.x;
    if (idx >= BB * CC * HW) return;
    int w = idx & 63, h = (idx >> 6) & 63;
    int c = (idx / HW) & 127, b = idx / (CC * HW);
    const float* xp = x + ((size_t)(b * CC + c)) * HW;
    const float2* gp = (const float2*)grid;
    float acc = 0.f;
#pragma unroll
    for (int t = 0; t < K2; ++t) {
        float2 g = gp[(((size_t)b * K2 + t)) * HW + h * WW + w];
        float gx = g.x, gy = g.y;
        float x0f = floorf(gx), y0f = floorf(gy);
        float wx1 = gx - x0f, wx0 = 1.f - wx1;
        float wy1 = gy - y0f, wy0 = 1.f - wy1;
        int ix0 = (int)x0f, iy0 = (int)y0f;
        int ix1 = ix0 + 1,  iy1 = iy0 + 1;
        float v00 = 0.f, v10 = 0.f, v01 = 0.f, v11 = 0.f;
        if ((unsigned)iy0 < HH) {
            const float* row = xp + (size_t)iy0 * WW;
            if ((unsigned)ix0 < WW) v00 = row[ix0];
            if ((unsigned)ix1 < WW) v10 = row[ix1];
        }
        if ((unsigned)iy1 < HH) {
            const float* row = xp + (size_t)iy1 * WW;
            if ((unsigned)ix0 < WW) v01 = row[ix0];
            if ((unsigned)ix1 < WW) v11 = row[ix1];
        }
        float bil = v00 * (wx0 * wy0) + v10 * (wx1 * wy0)
                  + v01 * (wx0 * wy1) + v11 * (wx1 * wy1);
        acc = fmaf(bil, wk[c * K2 + t], acc);
    }
    out[idx] = acc;
}

extern "C" void kernel_launch(void* const* d_in, const int* in_sizes, int n_in,
                              void* d_out, int out_size, void* d_ws, size_t ws_size,
                              hipStream_t stream) {
    const float* x    = (const float*)d_in[0];
    const float* offw = (const float*)d_in[1];
    const float* offb = (const float*)d_in[2];
    const float* wwk  = (const float*)d_in[3];
    float* out = (float*)d_out;

    const size_t XP_BYTES = (size_t)BB * PSTRIDE * sizeof(unsigned short); // 8.92 MB
    const size_t WF_BYTES = (size_t)144 * 512 * sizeof(unsigned short);    // 147 KB
    const size_t NEED = 2 * XP_BYTES + WF_BYTES;                           // 18.0 MB

    if (ws_size < NEED) {
        float* grid = (float*)d_ws;
        hipLaunchKernelGGL(offset_grid_kernel_fb, dim3(NPIX / 256), dim3(256),
                           0, stream, x, offw, offb, grid);
        hipLaunchKernelGGL(sample_kernel_fb, dim3((BB * CC * HW) / 256), dim3(256),
                           0, stream, x, grid, wwk, out);
        return;
    }

    // ws: [xPh][xPl][wF]
    char* p = (char*)d_ws;
    unsigned short* xPh = (unsigned short*)p;           p += XP_BYTES;
    unsigned short* xPl = (unsigned short*)p;           p += XP_BYTES;
    unsigned short* wF  = (unsigned short*)p;

    hipLaunchKernelGGL(prep_transpose_kernel,
                       dim3(TR_BLOCKS + WF_BLOCKS + BORDER_BLOCKS), dim3(256),
                       0, stream, x, offw, xPh, xPl, wF);
    hipLaunchKernelGGL(fused_conv_sample_kernel, dim3(512), dim3(256),
                       0, stream, xPh, xPl, wF, offb, wwk, out);
}

// Round 25
// 44.553 us; speedup vs baseline: 1.1450x; 1.0086x over previous
//
#include <hip/hip_runtime.h>

#define BB 8
#define CC 128
#define HH 64
#define WW 64
#define K2 9
#define NOFF 18
#define HW 4096          // HH*WW
#define NPIX 32768       // BB*HW
#define OPAD 32          // o padded to 32 (2 N-tiles)
#define HP 66            // padded spatial dim
#define PSTRIDE (HP*HP*CC)   // elems per batch (padded)

#define TR_BLOCKS     4096  // 128 p-tiles x 4 c-tiles x 8 b
#define WF_BLOCKS     288   // 144 frags x 512 elems / 256
#define BORDER_BLOCKS 260   // 2 bufs x 2080 cells x 16 uint4 / 256

#define GR_ROW 1056         // granules (16B) per row per buf: 66 px x 16
#define ROWSET_BYTES 33792  // 2 bufs x 1056 x 16

typedef __attribute__((ext_vector_type(8))) short bf16x8;
typedef __attribute__((ext_vector_type(4))) float f32x4;

__device__ __forceinline__ unsigned short f2bf(float f) {
    unsigned u = __float_as_uint(f);
    unsigned r = u + 0x7FFFu + ((u >> 16) & 1u);   // RNE
    return (unsigned short)(r >> 16);
}
__device__ __forceinline__ float bf2f(unsigned short h) {
    return __uint_as_float((unsigned)h << 16);
}

// ---------------------------------------------------------------------------
// K0: fused prep (R19-verified).
//  [0,TR)        : transpose x -> xPh/xPl (hi/lo, zero-padded [b][66][66][128])
//  [TR,+WF)      : weights -> wF fragment-major (contiguous 16B/lane reads)
//  [.., +BORDER) : zero the 1-px border of xPh/xPl
// ---------------------------------------------------------------------------
__global__ __launch_bounds__(256) void prep_transpose_kernel(
    const float* __restrict__ x, const float* __restrict__ offw,
    unsigned short* __restrict__ xPh, unsigned short* __restrict__ xPl,
    unsigned short* __restrict__ wF)
{
    __shared__ float tile[32][33];
    int bi = blockIdx.x;
    int tid = threadIdx.x;
    if (bi < TR_BLOCKS) {
        int p0 = (bi & 127) * 32;
        int c0 = ((bi >> 7) & 3) * 32;
        int b  = bi >> 9;
        int tx = tid & 31;
        int ty = tid >> 5;                 // 0..7
#pragma unroll
        for (int i = 0; i < 4; ++i)
            tile[ty + i * 8][tx] =
                x[((size_t)(b * CC + c0 + ty + i * 8)) * HW + p0 + tx];
        __syncthreads();
#pragma unroll
        for (int i = 0; i < 4; ++i) {
            int p = p0 + ty + i * 8;
            int h = p >> 6, w = p & 63;
            float v = tile[tx][ty + i * 8];
            unsigned short hi = f2bf(v);
            unsigned short lo = f2bf(v - bf2f(hi));
            size_t pidx = ((size_t)b * HP * HP + (size_t)(h + 1) * HP + (w + 1)) * CC + c0 + tx;
            xPh[pidx] = hi;
            xPl[pidx] = lo;
        }
    } else if (bi < TR_BLOCKS + WF_BLOCKS) {
        int e = (bi - TR_BLOCKS) * 256 + tid;   // 0..73727
        int fid = e >> 9;
        int r = e & 511;
        int lane = r >> 3;
        int elem = r & 7;
        int bufsel = fid & 1;
        int n   = (fid >> 1) & 1;
        int cwv = (fid >> 2) & 3;
        int j   = fid >> 4;
        int o = n * 16 + (lane & 15);
        int c = cwv * 32 + ((lane >> 4) << 3) + elem;
        float v = (o < NOFF) ? offw[((size_t)o * CC + c) * K2 + j] : 0.f;
        unsigned short hi = f2bf(v);
        wF[e] = bufsel ? f2bf(v - bf2f(hi)) : hi;
    } else {
        int i = (bi - TR_BLOCKS - WF_BLOCKS) * 256 + tid;   // 0..66559
        int bufsel = i >= 33280;
        int jj = i - bufsel * 33280;
        int cell = jj >> 4, q = jj & 15;
        int b = cell / 260, r = cell - b * 260;
        int hp, wp;
        if (r < 132) { hp = (r >= 66) ? (HP - 1) : 0; wp = (r >= 66) ? r - 66 : r; }
        else { int r2 = r - 132; wp = (r2 & 1) ? (HP - 1) : 0; hp = 1 + (r2 >> 1); }
        unsigned short* dst = bufsel ? xPl : xPh;
        uint4 z = {0u, 0u, 0u, 0u};
        *(uint4*)(dst + (((size_t)b * HP + hp) * HP + wp) * CC + q * 8) = z;
    }
}

// ---------------------------------------------------------------------------
// K1: FUSED offset-conv (MFMA, LDS-staged A) + bilinear sample — R20/R23
// verified structure and bounds (256,2). Phase 1: conv via contiguous staged
// rows + ds_read_b128 (XOR-swizzled). Phase 2: reduce + 576 bilinear records
// once per row (LDS only). Phase 3: gather + tap-weighted sum, 4 passes.
// ---------------------------------------------------------------------------
__global__ __launch_bounds__(256, 2) void fused_conv_sample_kernel(
    const unsigned short* __restrict__ xPh, const unsigned short* __restrict__ xPl,
    const unsigned short* __restrict__ wF, const float* __restrict__ offb,
    const float* __restrict__ wk, float* __restrict__ out)
{
    __shared__ __align__(16) unsigned char LDSB[ROWSET_BYTES];   // 33 KB (staging/red/acc_s)
    __shared__ float4 recW[576];   // 9.2 KB
    __shared__ int2   recI[576];   // 4.6 KB
    __shared__ float  swkT[K2 * CC];  // 4.6 KB
    int jx = blockIdx.x;        // 0..511
    int b = jx & 7;             // XCD-local batch
    int h = jx >> 3;            // 0..63
    int tid = threadIdx.x;
    int l = tid & 63;
    int cw = __builtin_amdgcn_readfirstlane(tid >> 6);   // 0..3 c-chunk
    int row  = l & 15;          // A: M-row ; B: o-col
    int kseg = l >> 4;          // 0..3
    int cslot = cw * 4 + kseg;  // 16B channel-slot

    // tap weights (transposed) — once per block
    for (int i = tid; i < K2 * CC; i += 256) {
        int c = i / 9, t = i - c * 9;
        swkT[t * CC + c] = wk[i];
    }

    f32x4 acc[4][2];
#pragma unroll
    for (int m = 0; m < 4; ++m)
#pragma unroll
        for (int n = 0; n < 2; ++n)
            acc[m][n] = (f32x4){0.f, 0.f, 0.f, 0.f};

    const unsigned short* xh = xPh + (size_t)b * PSTRIDE;
    const unsigned short* xl = xPl + (size_t)b * PSTRIDE;

    // ---------------- Phase 1: conv (R19 structure) ----------------
#pragma unroll 1
    for (int dh = 0; dh < 3; ++dh) {
        if (dh) __syncthreads();
        const unsigned short* rowh = xh + ((size_t)(h + dh) * HP) * CC;
        const unsigned short* rowl = xl + ((size_t)(h + dh) * HP) * CC;
#pragma unroll
        for (int it = 0; it < 9; ++it) {
            int G = it * 256 + tid;
            if (G < 2112) {
                int buf = G >= GR_ROW;
                int g = G - (buf ? GR_ROW : 0);
                int px = g >> 4, cg = g & 15;
                const unsigned short* src =
                    (buf ? rowl : rowh) + (size_t)px * CC + ((cg ^ (px & 7)) << 3);
                uint4 v = *(const uint4*)src;
                *(uint4*)(LDSB + (size_t)G * 16) = v;
            }
        }
        __syncthreads();
#pragma unroll
        for (int dw = 0; dw < 3; ++dw) {
            int j = dh * 3 + dw;
            int fbase = (j * 4 + cw) * 4;
            bf16x8 Bh0 = *(const bf16x8*)(wF + (size_t)(fbase + 0) * 512 + l * 8);
            bf16x8 Bl0 = *(const bf16x8*)(wF + (size_t)(fbase + 1) * 512 + l * 8);
            bf16x8 Bh1 = *(const bf16x8*)(wF + (size_t)(fbase + 2) * 512 + l * 8);
            bf16x8 Bl1 = *(const bf16x8*)(wF + (size_t)(fbase + 3) * 512 + l * 8);
#pragma unroll
            for (int m = 0; m < 4; ++m) {
                int px = m * 16 + row + dw;
                int gA = px * 16 + (cslot ^ (px & 7));
                bf16x8 Ah = *(const bf16x8*)(LDSB + (size_t)gA * 16);
                bf16x8 Al = *(const bf16x8*)(LDSB + (size_t)(GR_ROW + gA) * 16);
                acc[m][0] = __builtin_amdgcn_mfma_f32_16x16x32_bf16(Ah, Bh0, acc[m][0], 0, 0, 0);
                acc[m][0] = __builtin_amdgcn_mfma_f32_16x16x32_bf16(Al, Bh0, acc[m][0], 0, 0, 0);
                acc[m][0] = __builtin_amdgcn_mfma_f32_16x16x32_bf16(Ah, Bl0, acc[m][0], 0, 0, 0);
                acc[m][1] = __builtin_amdgcn_mfma_f32_16x16x32_bf16(Ah, Bh1, acc[m][1], 0, 0, 0);
                acc[m][1] = __builtin_amdgcn_mfma_f32_16x16x32_bf16(Al, Bh1, acc[m][1], 0, 0, 0);
                acc[m][1] = __builtin_amdgcn_mfma_f32_16x16x32_bf16(Ah, Bl1, acc[m][1], 0, 0, 0);
            }
        }
    }

    // ---------------- Phase 2: reduce + records (once per row) ----------------
    __syncthreads();
    float (*red)[OPAD][65] = (float (*)[OPAD][65])LDSB;   // aliases staging
#pragma unroll
    for (int m = 0; m < 4; ++m)
#pragma unroll
        for (int n = 0; n < 2; ++n)
#pragma unroll
            for (int r = 0; r < 4; ++r)
                red[cw][n * 16 + row][m * 16 + kseg * 4 + r] = acc[m][n][r];
    __syncthreads();

    float base_y = -1.f + (2.f / (HH - 1)) * (float)h;
    for (int item = tid; item < 576; item += 256) {
        int p = item & 63;
        int t = item >> 6;       // 0..8
        float sx = offb[t]
                 + red[0][t][p] + red[1][t][p] + red[2][t][p] + red[3][t][p];
        float sy = offb[t + K2]
                 + red[0][t + K2][p] + red[1][t + K2][p]
                 + red[2][t + K2][p] + red[3][t + K2][p];
        float base_x = -1.f + (2.f / (WW - 1)) * (float)p;
        float gx = ((sx + base_x + 1.f) * (float)WW - 1.f) * 0.5f;
        float gy = ((sy + base_y + 1.f) * (float)HH - 1.f) * 0.5f;

        float x0f = floorf(gx), y0f = floorf(gy);
        float wx1 = gx - x0f, wx0 = 1.f - wx1;
        float wy1 = gy - y0f, wy0 = 1.f - wy1;
        int ix0 = (int)x0f, iy0 = (int)y0f;
        int ix1 = ix0 + 1,  iy1 = iy0 + 1;
        float ax0 = ((unsigned)ix0 < WW) ? wx0 : 0.f;
        float ax1 = ((unsigned)ix1 < WW) ? wx1 : 0.f;
        float ay0 = ((unsigned)iy0 < HH) ? wy0 : 0.f;
        float ay1 = ((unsigned)iy1 < HH) ? wy1 : 0.f;
        int cx0 = min(max(ix0, 0), WW - 1) + 1, cx1 = min(max(ix1, 0), WW - 1) + 1;
        int cy0 = min(max(iy0, 0), HH - 1) + 1, cy1 = min(max(iy1, 0), HH - 1) + 1;
        int o00 = cy0 * HP + cx0, o10 = cy0 * HP + cx1;
        int o01 = cy1 * HP + cx0, o11 = cy1 * HP + cx1;
        recW[t * 64 + p] = make_float4(ax0 * ay0, ax1 * ay0, ax0 * ay1, ax1 * ay1);
        recI[t * 64 + p] = make_int2(o00 | (o10 << 16), o01 | (o11 << 16));
    }
    __syncthreads();

    // ---------------- Phase 3: gather + tap-weighted sum ----------------
    int c8     = (tid & 15) * 8;
    int slot16 = tid >> 4;           // 0..15
    const unsigned short* xb = xh;   // padded hi buffer
    float* acc_s = (float*)LDSB;     // 16*132 floats, aliases dead staging

    float4 wkA[K2], wkB[K2];
#pragma unroll
    for (int t = 0; t < K2; ++t) {
        wkA[t] = *(const float4*)&swkT[t * CC + c8];
        wkB[t] = *(const float4*)&swkT[t * CC + c8 + 4];
    }

#pragma unroll 1
    for (int pp = 0; pp < 4; ++pp) {
        int slot = pp * 16 + slot16;
        float acc8[8];
#pragma unroll
        for (int i = 0; i < 8; ++i) acc8[i] = 0.f;
#pragma unroll
        for (int t = 0; t < K2; ++t) {
            int r = t * 64 + slot;
            float4 wv = recW[r];
            int2   iv = recI[r];
            uint4 u00 = *(const uint4*)(xb + (((iv.x & 0xFFFF) << 7) + c8));
            uint4 u10 = *(const uint4*)(xb + (((iv.x >> 16)     << 7) + c8));
            uint4 u01 = *(const uint4*)(xb + (((iv.y & 0xFFFF) << 7) + c8));
            uint4 u11 = *(const uint4*)(xb + (((iv.y >> 16)     << 7) + c8));
            const unsigned* p00 = (const unsigned*)&u00;
            const unsigned* p10 = (const unsigned*)&u10;
            const unsigned* p01 = (const unsigned*)&u01;
            const unsigned* p11 = (const unsigned*)&u11;
#pragma unroll
            for (int g = 0; g < 4; ++g) {
                float v00a = __uint_as_float(p00[g] << 16);
                float v00b = __uint_as_float(p00[g] & 0xFFFF0000u);
                float v10a = __uint_as_float(p10[g] << 16);
                float v10b = __uint_as_float(p10[g] & 0xFFFF0000u);
                float v01a = __uint_as_float(p01[g] << 16);
                float v01b = __uint_as_float(p01[g] & 0xFFFF0000u);
                float v11a = __uint_as_float(p11[g] << 16);
                float v11b = __uint_as_float(p11[g] & 0xFFFF0000u);
                float bila = fmaf(v00a, wv.x, fmaf(v10a, wv.y, fmaf(v01a, wv.z, v11a * wv.w)));
                float bilb = fmaf(v00b, wv.x, fmaf(v10b, wv.y, fmaf(v01b, wv.z, v11b * wv.w)));
                float wka = (g < 2) ? ((g == 0) ? wkA[t].x : wkA[t].z)
                                    : ((g == 2) ? wkB[t].x : wkB[t].z);
                float wkb = (g < 2) ? ((g == 0) ? wkA[t].y : wkA[t].w)
                                    : ((g == 2) ? wkB[t].y : wkB[t].w);
                acc8[g * 2]     = fmaf(bila, wka, acc8[g * 2]);
                acc8[g * 2 + 1] = fmaf(bilb, wkb, acc8[g * 2 + 1]);
            }
        }
        __syncthreads();   // acc_s free (prev pp reads done / staging dead)
        *(float4*)&acc_s[slot16 * 132 + c8]     = make_float4(acc8[0], acc8[1], acc8[2], acc8[3]);
        *(float4*)&acc_s[slot16 * 132 + c8 + 4] = make_float4(acc8[4], acc8[5], acc8[6], acc8[7]);
        __syncthreads();
#pragma unroll
        for (int r = 0; r < 8; ++r) {
            int cs   = r * 16 + (tid >> 4);
            int wloc = tid & 15;
            out[((size_t)(b * CC + cs)) * HW + h * WW + pp * 16 + wloc] =
                acc_s[wloc * 132 + cs];
        }
    }
}

// ---------------------------------------------------------------------------
// Fallback (round-1 pipeline, needs only 2.36 MB ws) — defensive only.
// ---------------------------------------------------------------------------
__global__ __launch_bounds__(256) void offset_grid_kernel_fb(
    const float* __restrict__ x, const float* __restrict__ offw,
    const float* __restrict__ offb, float* __restrict__ grid)
{
    int idx = blockIdx.x * blockDim.x + threadIdx.x;
    if (idx >= NPIX) return;
    int w = idx & 63, h = (idx >> 6) & 63, b = idx >> 12;
    float acc[NOFF];
#pragma unroll
    for (int o = 0; o < NOFF; ++o) acc[o] = offb[o];
    for (int c = 0; c < CC; ++c) {
        const float* xp = x + ((size_t)(b * CC + c)) * HW;
        float xv[9];
#pragma unroll
        for (int dh = -1; dh <= 1; ++dh)
#pragma unroll
            for (int dw = -1; dw <= 1; ++dw) {
                int hh = h + dh, ww2 = w + dw;
                float v = 0.f;
                if (hh >= 0 && hh < HH && ww2 >= 0 && ww2 < WW) v = xp[hh * WW + ww2];
                xv[(dh + 1) * 3 + (dw + 1)] = v;
            }
#pragma unroll
        for (int o = 0; o < NOFF; ++o) {
            const float* wp = offw + (size_t)(o * CC + c) * 9;
#pragma unroll
            for (int jj = 0; jj < 9; ++jj) acc[o] = fmaf(xv[jj], wp[jj], acc[o]);
        }
    }
    float base_x = -1.f + (2.f / (WW - 1)) * (float)w;
    float base_y = -1.f + (2.f / (HH - 1)) * (float)h;
#pragma unroll
    for (int t = 0; t < K2; ++t) {
        float gx = ((acc[t]      + base_x + 1.f) * (float)WW - 1.f) * 0.5f;
        float gy = ((acc[K2 + t] + base_y + 1.f) * (float)HH - 1.f) * 0.5f;
        size_t gi = ((((size_t)b * K2 + t) * HH + h) * WW + w) * 2;
        grid[gi] = gx; grid[gi + 1] = gy;
    }
}

__global__ __launch_bounds__(256) void sample_kernel_fb(
    const float* __restrict__ x, const float* __restrict__ grid,
    const float* __restrict__ wk, float* __restrict__ out)
{
    int idx = blockIdx.x * blockDim.x + threadIdx.x;
    if (idx >= BB * CC * HW) return;
    int w = idx & 63, h = (idx >> 6) & 63;
    int c = (idx / HW) & 127, b = idx / (CC * HW);
    const float* xp = x + ((size_t)(b * CC + c)) * HW;
    const float2* gp = (const float2*)grid;
    float acc = 0.f;
#pragma unroll
    for (int t = 0; t < K2; ++t) {
        float2 g = gp[(((size_t)b * K2 + t)) * HW + h * WW + w];
        float gx = g.x, gy = g.y;
        float x0f = floorf(gx), y0f = floorf(gy);
        float wx1 = gx - x0f, wx0 = 1.f - wx1;
        float wy1 = gy - y0f, wy0 = 1.f - wy1;
        int ix0 = (int)x0f, iy0 = (int)y0f;
        int ix1 = ix0 + 1,  iy1 = iy0 + 1;
        float v00 = 0.f, v10 = 0.f, v01 = 0.f, v11 = 0.f;
        if ((unsigned)iy0 < HH) {
            const float* row = xp + (size_t)iy0 * WW;
            if ((unsigned)ix0 < WW) v00 = row[ix0];
            if ((unsigned)ix1 < WW) v10 = row[ix1];
        }
        if ((unsigned)iy1 < HH) {
            const float* row = xp + (size_t)iy1 * WW;
            if ((unsigned)ix0 < WW) v01 = row[ix0];
            if ((unsigned)ix1 < WW) v11 = row[ix1];
        }
        float bil = v00 * (wx0 * wy0) + v10 * (wx1 * wy0)
                  + v01 * (wx0 * wy1) + v11 * (wx1 * wy1);
        acc = fmaf(bil, wk[c * K2 + t], acc);
    }
    out[idx] = acc;
}

extern "C" void kernel_launch(void* const* d_in, const int* in_sizes, int n_in,
                              void* d_out, int out_size, void* d_ws, size_t ws_size,
                              hipStream_t stream) {
    const float* x    = (const float*)d_in[0];
    const float* offw = (const float*)d_in[1];
    const float* offb = (const float*)d_in[2];
    const float* wwk  = (const float*)d_in[3];
    float* out = (float*)d_out;

    const size_t XP_BYTES = (size_t)BB * PSTRIDE * sizeof(unsigned short); // 8.92 MB
    const size_t WF_BYTES = (size_t)144 * 512 * sizeof(unsigned short);    // 147 KB
    const size_t NEED = 2 * XP_BYTES + WF_BYTES;                           // 18.0 MB

    if (ws_size < NEED) {
        float* grid = (float*)d_ws;
        hipLaunchKernelGGL(offset_grid_kernel_fb, dim3(NPIX / 256), dim3(256),
                           0, stream, x, offw, offb, grid);
        hipLaunchKernelGGL(sample_kernel_fb, dim3((BB * CC * HW) / 256), dim3(256),
                           0, stream, x, grid, wwk, out);
        return;
    }

    // ws: [xPh][xPl][wF]
    char* p = (char*)d_ws;
    unsigned short* xPh = (unsigned short*)p;           p += XP_BYTES;
    unsigned short* xPl = (unsigned short*)p;           p += XP_BYTES;
    unsigned short* wF  = (unsigned short*)p;

    hipLaunchKernelGGL(prep_transpose_kernel,
                       dim3(TR_BLOCKS + WF_BLOCKS + BORDER_BLOCKS), dim3(256),
                       0, stream, x, offw, xPh, xPl, wF);
    hipLaunchKernelGGL(fused_conv_sample_kernel, dim3(512), dim3(256),
                       0, stream, xPh, xPl, wF, offb, wwk, out);
}